// Round 3
// baseline (387.289 us; speedup 1.0000x reference)
//
#include <hip/hip_runtime.h>

// MLLoss: per-row hinge-margin loss over [B,16] fp32 distances, label-selected,
// mean-reduced to a scalar. Memory-bound: 256 MB distances + 32 MB labels.
//
// R6: revert R4's NT-load removal (regression 358->377: the harness's 1 GiB
// poison fills thrash L3 between replays, so there is no cross-replay cache
// residency to win, and plain loads churn L2/L3 allocation against the
// fill-dirtied cache. __builtin_nontemporal_load streams at full HBM read
// rate -> keep it). Additionally drop the second reduction kernel: a 1-block
// pre-kernel zeroes out[0] (the harness poisons it), then each block does one
// device-scope atomicAdd of its pre-scaled partial. Saves the mlloss_final
// launch + 16 KB readback (~3-5 us of the ~35 us kernel slice).
//
// Layout: 4 lanes per row ("quad"), each lane loads one 16 B vector so every
// load is perfectly coalesced (64 lanes x 16 B contiguous per wave).
// hinge_sum reduced inside the quad with 2 shfl_xor. All 4 quad lanes load the
// row's labels (same address -> HW broadcast) so control flow is uniform and
// #pragma unroll 4 gives 4 independent global-load chains per thread.

typedef float vfloat4 __attribute__((ext_vector_type(4)));

#define BLOCKS  4096
#define THREADS 256

__global__ __launch_bounds__(64) void mlloss_zero(float* __restrict__ out)
{
    if (threadIdx.x == 0) out[0] = 0.0f;
}

__global__ __launch_bounds__(THREADS) void mlloss_partial(
    const vfloat4* __restrict__ dist4,  // B*4 vfloat4 (16 floats/row)
    const int*     __restrict__ doctor, // [B] 0=control 1=parkinson 2=unknown
    const int*     __restrict__ real,   // [B] 0=control 1=parkinson
    float* __restrict__ out,            // [1] zeroed by mlloss_zero
    int B, float invB)
{
    const int g       = blockIdx.x * blockDim.x + threadIdx.x;
    const int lane4   = threadIdx.x & 3;             // vector index within row
    const int qstride = (gridDim.x * blockDim.x) >> 2;

    float acc = 0.0f;

    #pragma unroll 4
    for (int q = (g >> 2); q < B; q += qstride) {
        vfloat4 d = __builtin_nontemporal_load(&dist4[(size_t)q * 4 + lane4]);
        int doc   = __builtin_nontemporal_load(&doctor[q]);  // same addr for
        int re    = __builtin_nontemporal_load(&real[q]);    // all 4 quad lanes

        float h0 = fmaxf(1.0f - d.x, 0.0f);
        float h1 = fmaxf(1.0f - d.y, 0.0f);
        float h2 = fmaxf(1.0f - d.z, 0.0f);
        float h3 = fmaxf(1.0f - d.w, 0.0f);
        float s  = (h0 + h1) + (h2 + h3);

        // hinge_sum across the 4 lanes of this quad
        s += __shfl_xor(s, 1);
        s += __shfl_xor(s, 2);

        // lane with lane4==0 holds row elements 0..3: d.x=d[0], d.y=d[1]
        float loss_c = d.x + s - h0;                 // doctor == control
        float loss_p = d.y + s - h1;                 // doctor == parkinson
        float loss_u = (re == 0) ? h1 : h0;          // doctor == unknown
        float loss   = (doc == 0) ? loss_c : ((doc == 1) ? loss_p : loss_u);
        acc += (lane4 == 0) ? loss : 0.0f;
    }

    // wave (64-lane) reduction
    #pragma unroll
    for (int m = 32; m >= 1; m >>= 1)
        acc += __shfl_xor(acc, m);

    __shared__ float wsum[THREADS / 64];
    const int wid = threadIdx.x >> 6;
    if ((threadIdx.x & 63) == 0) wsum[wid] = acc;
    __syncthreads();

    if (threadIdx.x == 0) {
        float t = 0.0f;
        #pragma unroll
        for (int w = 0; w < THREADS / 64; ++w) t += wsum[w];
        atomicAdd(out, t * invB);    // device-scope; 4096 adds to one address
    }
}

extern "C" void kernel_launch(void* const* d_in, const int* in_sizes, int n_in,
                              void* d_out, int out_size, void* d_ws, size_t ws_size,
                              hipStream_t stream) {
    const vfloat4* dist4  = (const vfloat4*)d_in[0];
    const int*     doctor = (const int*)d_in[1];
    const int*     real_l = (const int*)d_in[2];
    float*         out    = (float*)d_out;

    const int B = in_sizes[1];             // doctor_labels element count

    mlloss_zero<<<1, 64, 0, stream>>>(out);
    mlloss_partial<<<BLOCKS, THREADS, 0, stream>>>(
        dist4, doctor, real_l, out, B, 1.0f / (float)B);
}

// Round 4
// 359.773 us; speedup vs baseline: 1.0765x; 1.0765x over previous
//
#include <hip/hip_runtime.h>

// MLLoss: per-row hinge-margin loss over [B,16] fp32 distances, label-selected,
// mean-reduced to a scalar. Memory-bound: 256 MB distances + 32 MB labels.
//
// R7 == exact revert to the verified-best R3 (358.0 us). Post-mortems:
//  - R4 (plain loads, no NT): +19 us. The harness's 1 GiB poison fills thrash
//    L3 between replays -> no cross-replay residency to win; plain loads churn
//    allocation against the fill-dirtied cache. NT loads stream at HBM read
//    rate. KEEP __builtin_nontemporal_load.
//  - R6 (atomicAdd finish, no final kernel): +29 us vs R3. 4096 same-address
//    device-scope float RMWs serialize at the cross-XCD coherence point
//    (~30 us burst at dispatch end). KEEP the two-kernel partials reduction.
// Kernel slice ~36 us for 288 MB compulsory = ~7.6 TB/s (>=95% of HBM read
// ceiling); the other ~320 us of dur_us is the harness's two 1 GiB poison
// fills, outside kernel_launch's control.
//
// Layout: 4 lanes per row ("quad"), each lane loads one 16 B vector so every
// load is perfectly coalesced (64 lanes x 16 B contiguous per wave).
// hinge_sum reduced inside the quad with 2 shfl_xor. All 4 quad lanes load the
// row's labels (same address -> HW broadcast) so control flow is uniform and
// #pragma unroll 4 gives 4 independent global-load chains per thread.
// Phase 1 writes one pre-scaled partial per block to d_ws; phase 2 (1 block)
// reduces 4096 partials and stores the scalar -> no memset, no atomics.

typedef float vfloat4 __attribute__((ext_vector_type(4)));

#define BLOCKS  4096
#define THREADS 256

__global__ __launch_bounds__(THREADS) void mlloss_partial(
    const vfloat4* __restrict__ dist4,  // B*4 vfloat4 (16 floats/row)
    const int*     __restrict__ doctor, // [B] 0=control 1=parkinson 2=unknown
    const int*     __restrict__ real,   // [B] 0=control 1=parkinson
    float* __restrict__ partials,       // [gridDim.x]
    int B, float invB)
{
    const int g       = blockIdx.x * blockDim.x + threadIdx.x;
    const int lane4   = threadIdx.x & 3;             // vector index within row
    const int qstride = (gridDim.x * blockDim.x) >> 2;

    float acc = 0.0f;

    #pragma unroll 4
    for (int q = (g >> 2); q < B; q += qstride) {
        vfloat4 d = __builtin_nontemporal_load(&dist4[(size_t)q * 4 + lane4]);
        int doc   = __builtin_nontemporal_load(&doctor[q]);  // same addr for
        int re    = __builtin_nontemporal_load(&real[q]);    // all 4 quad lanes

        float h0 = fmaxf(1.0f - d.x, 0.0f);
        float h1 = fmaxf(1.0f - d.y, 0.0f);
        float h2 = fmaxf(1.0f - d.z, 0.0f);
        float h3 = fmaxf(1.0f - d.w, 0.0f);
        float s  = (h0 + h1) + (h2 + h3);

        // hinge_sum across the 4 lanes of this quad
        s += __shfl_xor(s, 1);
        s += __shfl_xor(s, 2);

        // lane with lane4==0 holds row elements 0..3: d.x=d[0], d.y=d[1]
        float loss_c = d.x + s - h0;                 // doctor == control
        float loss_p = d.y + s - h1;                 // doctor == parkinson
        float loss_u = (re == 0) ? h1 : h0;          // doctor == unknown
        float loss   = (doc == 0) ? loss_c : ((doc == 1) ? loss_p : loss_u);
        acc += (lane4 == 0) ? loss : 0.0f;
    }

    // wave (64-lane) reduction
    #pragma unroll
    for (int m = 32; m >= 1; m >>= 1)
        acc += __shfl_xor(acc, m);

    __shared__ float wsum[THREADS / 64];
    const int wid = threadIdx.x >> 6;
    if ((threadIdx.x & 63) == 0) wsum[wid] = acc;
    __syncthreads();

    if (threadIdx.x == 0) {
        float t = 0.0f;
        #pragma unroll
        for (int w = 0; w < THREADS / 64; ++w) t += wsum[w];
        partials[blockIdx.x] = t * invB;             // pre-scaled, ~1e-3 each
    }
}

__global__ __launch_bounds__(THREADS) void mlloss_final(
    const float* __restrict__ partials, float* __restrict__ out, int n)
{
    float acc = 0.0f;
    for (int i = threadIdx.x; i < n; i += THREADS)
        acc += partials[i];

    #pragma unroll
    for (int m = 32; m >= 1; m >>= 1)
        acc += __shfl_xor(acc, m);

    __shared__ float wsum[THREADS / 64];
    const int wid = threadIdx.x >> 6;
    if ((threadIdx.x & 63) == 0) wsum[wid] = acc;
    __syncthreads();

    if (threadIdx.x == 0) {
        float t = 0.0f;
        #pragma unroll
        for (int w = 0; w < THREADS / 64; ++w) t += wsum[w];
        out[0] = t;
    }
}

extern "C" void kernel_launch(void* const* d_in, const int* in_sizes, int n_in,
                              void* d_out, int out_size, void* d_ws, size_t ws_size,
                              hipStream_t stream) {
    const vfloat4* dist4  = (const vfloat4*)d_in[0];
    const int*     doctor = (const int*)d_in[1];
    const int*     real_l = (const int*)d_in[2];
    float*         out    = (float*)d_out;
    float*         part   = (float*)d_ws;  // 4096 floats = 16 KB scratch

    const int B = in_sizes[1];             // doctor_labels element count

    mlloss_partial<<<BLOCKS, THREADS, 0, stream>>>(
        dist4, doctor, real_l, part, B, 1.0f / (float)B);
    mlloss_final<<<1, THREADS, 0, stream>>>(part, out, BLOCKS);
}